// Round 2
// baseline (1261.642 us; speedup 1.0000x reference)
//
#include <hip/hip_runtime.h>

// Modulated deformable conv2d, fp32.
// B=4, C=64, H=W=128, O=64, K=3x3, stride=1, pad=1, dil=1, og=1, groups=1.
//
// Round 2: fix the 1-wave/SIMD latency problem of round 1.
// Block = 256 threads (4 waves). All 4 waves cover the SAME 64 consecutive
// pixels (lane = pixel), but each wave takes 16 of the 64 input channels, so
// gathers are NOT duplicated. Each thread keeps acc[64] (all output channels,
// partial over its c-range); partials are combined via ds_add_f32 into a
// 64x64 fp32 LDS tile laid out [o][lane] (lane stride 4B -> conflict-free).
// __launch_bounds__(256,3): VGPR<=170 -> 3 blocks/CU = 3 waves/SIMD TLP.

#define BB 4
#define CC 64
#define HH 128
#define WW 128
#define OO 64
#define KHW 3
#define KK 9
#define HW (HH * WW)
#define CPW 16  // channels per wave

__global__ void transpose_w_kernel(const float* __restrict__ w,
                                   float* __restrict__ wt) {
    int i = blockIdx.x * blockDim.x + threadIdx.x;
    if (i >= OO * CC * KK) return;
    // wt layout: [(c*9+k)*64 + o]
    int o  = i & (OO - 1);
    int ck = i >> 6;
    int c  = ck / KK;
    int k  = ck - c * KK;
    wt[i] = w[(o * CC + c) * KK + k];
}

__global__ __launch_bounds__(256, 3) void deform_conv_kernel(
    const float* __restrict__ x, const float* __restrict__ offset,
    const float* __restrict__ mask, const float* __restrict__ wt,
    const float* __restrict__ bias, float* __restrict__ out) {
    const int wv = threadIdx.x >> 6;        // wave id: c-chunk
    const int l  = threadIdx.x & 63;        // lane: pixel within block
    const int b        = blockIdx.x >> 8;   // 256 blocks per image (HW/64)
    const int blockRem = (blockIdx.x << 6) & (HW - 1);
    const int rem = blockRem + l;
    const int ho = rem >> 7;
    const int wo = rem & (WW - 1);

    __shared__ float red[OO * 64];          // [o][lane], 16 KB
    for (int i = threadIdx.x; i < OO * 64; i += 256) red[i] = 0.0f;

    // Per-tap sampling setup: 4 corner element-offsets + 4 folded weights.
    int   addr[KK][4];
    float wgt[KK][4];
    const float* xb = x + b * (CC * HW);

#pragma unroll
    for (int k = 0; k < KK; ++k) {
        float offy = offset[((b * (2 * KK) + 2 * k) * HW) + rem];
        float offx = offset[((b * (2 * KK) + 2 * k + 1) * HW) + rem];
        float m    = mask[((b * KK + k) * HW) + rem];
        float py = offy + (float)(k / KHW) + (float)(ho - 1);
        float px = offx + (float)(k % KHW) + (float)(wo - 1);
        float fy0 = floorf(py), fx0 = floorf(px);
        float ly = py - fy0, lx = px - fx0;
        int y0 = (int)fy0, x0 = (int)fx0;
        int y1 = y0 + 1, x1 = x0 + 1;
        bool vy0 = (y0 >= 0) && (y0 < HH);
        bool vy1 = (y1 >= 0) && (y1 < HH);
        bool vx0 = (x0 >= 0) && (x0 < WW);
        bool vx1 = (x1 >= 0) && (x1 < WW);
        int cy0 = min(max(y0, 0), HH - 1), cy1 = min(max(y1, 0), HH - 1);
        int cx0 = min(max(x0, 0), WW - 1), cx1 = min(max(x1, 0), WW - 1);
        addr[k][0] = cy0 * WW + cx0;
        addr[k][1] = cy0 * WW + cx1;
        addr[k][2] = cy1 * WW + cx0;
        addr[k][3] = cy1 * WW + cx1;
        wgt[k][0] = (vy0 && vx0) ? m * (1.0f - ly) * (1.0f - lx) : 0.0f;
        wgt[k][1] = (vy0 && vx1) ? m * (1.0f - ly) * lx : 0.0f;
        wgt[k][2] = (vy1 && vx0) ? m * ly * (1.0f - lx) : 0.0f;
        wgt[k][3] = (vy1 && vx1) ? m * ly * lx : 0.0f;
    }

    __syncthreads();  // LDS zeroing complete before any ds_add

    float acc[OO];
#pragma unroll
    for (int o = 0; o < OO; ++o) acc[o] = 0.0f;

    const int c0 = wv * CPW;
    for (int c = c0; c < c0 + CPW; ++c) {
        const float* xc = xb + c * HW;
        float val[KK];
#pragma unroll
        for (int k = 0; k < KK; ++k) {
            val[k] = wgt[k][0] * xc[addr[k][0]] + wgt[k][1] * xc[addr[k][1]] +
                     wgt[k][2] * xc[addr[k][2]] + wgt[k][3] * xc[addr[k][3]];
        }
        const float* wrow = wt + c * (KK * OO);  // wave-uniform -> s_load
#pragma unroll
        for (int k = 0; k < KK; ++k) {
#pragma unroll
            for (int o = 0; o < OO; ++o) {
                acc[o] = fmaf(val[k], wrow[k * OO + o], acc[o]);
            }
        }
    }

    // Reduce partials across the 4 waves. [o][lane] -> lane stride 4B.
#pragma unroll
    for (int o = 0; o < OO; ++o) {
        atomicAdd(&red[o * 64 + l], acc[o]);  // ds_add_f32
    }
    __syncthreads();

    // Epilogue: wave wv writes outs [wv*16, wv*16+16); lanes -> consecutive
    // pixels -> coalesced 256B stores.
#pragma unroll
    for (int i = 0; i < CPW; ++i) {
        int o = wv * CPW + i;
        out[(b * OO + o) * HW + rem] = red[o * 64 + l] + bias[o];
    }
}

extern "C" void kernel_launch(void* const* d_in, const int* in_sizes, int n_in,
                              void* d_out, int out_size, void* d_ws,
                              size_t ws_size, hipStream_t stream) {
    const float* x      = (const float*)d_in[0];
    const float* offset = (const float*)d_in[1];
    const float* mask   = (const float*)d_in[2];
    const float* weight = (const float*)d_in[3];
    const float* bias   = (const float*)d_in[4];
    float* out = (float*)d_out;
    float* wt  = (float*)d_ws;  // 64*576*4 = 147456 bytes

    int nw = OO * CC * KK;
    transpose_w_kernel<<<(nw + 255) / 256, 256, 0, stream>>>(weight, wt);

    int nblocks = (BB * HW) / 64;  // 4096 blocks... no: 65536/64 = 1024
    deform_conv_kernel<<<nblocks, 256, 0, stream>>>(x, offset, mask, wt, bias,
                                                    out);
}

// Round 3
// 488.535 us; speedup vs baseline: 2.5825x; 2.5825x over previous
//
#include <hip/hip_runtime.h>

// Modulated deformable conv2d, fp32.
// B=4, C=64, H=W=128, O=64, K=3x3, stride=1, pad=1, dil=1, og=1, groups=1.
//
// Round 3: TLP from the grid, low register pressure, no LDS.
// One wave per block. Each block = (64 consecutive pixels) x (16 of 64 output
// channels). Grid = 1024 pixel-blocks x 4 o-chunks = 4096 waves = 4 waves/SIMD.
// Per-thread state: addr[36] + wgt[36] + val[9] + acc[16] ~= 110 VGPRs, under
// the 128-reg cap of __launch_bounds__(64,4) -> no spills (round-2 lesson:
// spills at VGPR=84 cost 10x). o-chunk comes from blockIdx -> weight addresses
// are block-uniform -> s_load weights, pure v_fmac GEMM stream.
// Gathers duplicated x4 across o-chunks; they are L1/L2-resident and VMEM
// issue (~37k instr/CU) is well under the ~92k VALU cycles/SIMD.

#define BB 4
#define CC 64
#define HH 128
#define WW 128
#define OO 64
#define KHW 3
#define KK 9
#define HW (HH * WW)
#define OPB 16  // output channels per block

__global__ void transpose_w_kernel(const float* __restrict__ w,
                                   float* __restrict__ wt) {
    int i = blockIdx.x * blockDim.x + threadIdx.x;
    if (i >= OO * CC * KK) return;
    // wt layout: [(c*9+k)*64 + o]
    int o  = i & (OO - 1);
    int ck = i >> 6;
    int c  = ck / KK;
    int k  = ck - c * KK;
    wt[i] = w[(o * CC + c) * KK + k];
}

__global__ __launch_bounds__(64, 4) void deform_conv_kernel(
    const float* __restrict__ x, const float* __restrict__ offset,
    const float* __restrict__ mask, const float* __restrict__ wt,
    const float* __restrict__ bias, float* __restrict__ out) {
    const int l        = threadIdx.x;           // lane = pixel within group
    const int ochunk   = blockIdx.x & 3;        // block-uniform o-chunk
    const int pixBlock = blockIdx.x >> 2;       // 1024 pixel groups
    const int b   = pixBlock >> 8;              // 256 groups per image
    const int rem = ((pixBlock & 255) << 6) + l;
    const int ho  = rem >> 7;
    const int wo  = rem & (WW - 1);

    // Per-tap sampling setup: 4 corner element-offsets + 4 folded weights.
    int   addr[KK][4];
    float wgt[KK][4];
    const float* xb = x + b * (CC * HW);

#pragma unroll
    for (int k = 0; k < KK; ++k) {
        float offy = offset[((b * (2 * KK) + 2 * k) * HW) + rem];
        float offx = offset[((b * (2 * KK) + 2 * k + 1) * HW) + rem];
        float m    = mask[((b * KK + k) * HW) + rem];
        float py = offy + (float)(k / KHW) + (float)(ho - 1);
        float px = offx + (float)(k % KHW) + (float)(wo - 1);
        float fy0 = floorf(py), fx0 = floorf(px);
        float ly = py - fy0, lx = px - fx0;
        int y0 = (int)fy0, x0 = (int)fx0;
        int y1 = y0 + 1, x1 = x0 + 1;
        bool vy0 = (y0 >= 0) && (y0 < HH);
        bool vy1 = (y1 >= 0) && (y1 < HH);
        bool vx0 = (x0 >= 0) && (x0 < WW);
        bool vx1 = (x1 >= 0) && (x1 < WW);
        int cy0 = min(max(y0, 0), HH - 1), cy1 = min(max(y1, 0), HH - 1);
        int cx0 = min(max(x0, 0), WW - 1), cx1 = min(max(x1, 0), WW - 1);
        addr[k][0] = cy0 * WW + cx0;
        addr[k][1] = cy0 * WW + cx1;
        addr[k][2] = cy1 * WW + cx0;
        addr[k][3] = cy1 * WW + cx1;
        wgt[k][0] = (vy0 && vx0) ? m * (1.0f - ly) * (1.0f - lx) : 0.0f;
        wgt[k][1] = (vy0 && vx1) ? m * (1.0f - ly) * lx : 0.0f;
        wgt[k][2] = (vy1 && vx0) ? m * ly * (1.0f - lx) : 0.0f;
        wgt[k][3] = (vy1 && vx1) ? m * ly * lx : 0.0f;
    }

    const int obase = ochunk * OPB;
    float acc[OPB];
#pragma unroll
    for (int oi = 0; oi < OPB; ++oi) acc[oi] = bias[obase + oi];

    for (int c = 0; c < CC; ++c) {
        const float* xc = xb + c * HW;
        float val[KK];
#pragma unroll
        for (int k = 0; k < KK; ++k) {
            val[k] = wgt[k][0] * xc[addr[k][0]] + wgt[k][1] * xc[addr[k][1]] +
                     wgt[k][2] * xc[addr[k][2]] + wgt[k][3] * xc[addr[k][3]];
        }
        // Block-uniform weight row -> scalar loads (s_load_dwordx4).
        const float* wrow = wt + c * (KK * OO) + obase;
#pragma unroll
        for (int k = 0; k < KK; ++k) {
#pragma unroll
            for (int oi = 0; oi < OPB; ++oi) {
                acc[oi] = fmaf(val[k], wrow[k * OO + oi], acc[oi]);
            }
        }
    }

    float* ob = out + (b * OO + obase) * HW + rem;
#pragma unroll
    for (int oi = 0; oi < OPB; ++oi) ob[oi * HW] = acc[oi];  // coalesced
}

extern "C" void kernel_launch(void* const* d_in, const int* in_sizes, int n_in,
                              void* d_out, int out_size, void* d_ws,
                              size_t ws_size, hipStream_t stream) {
    const float* x      = (const float*)d_in[0];
    const float* offset = (const float*)d_in[1];
    const float* mask   = (const float*)d_in[2];
    const float* weight = (const float*)d_in[3];
    const float* bias   = (const float*)d_in[4];
    float* out = (float*)d_out;
    float* wt  = (float*)d_ws;  // 64*576*4 = 147456 bytes

    int nw = OO * CC * KK;
    transpose_w_kernel<<<(nw + 255) / 256, 256, 0, stream>>>(weight, wt);

    int nblocks = (BB * HW / 64) * (OO / OPB);  // 1024 * 4 = 4096
    deform_conv_kernel<<<nblocks, 64, 0, stream>>>(x, offset, mask, wt, bias,
                                                   out);
}

// Round 4
// 482.361 us; speedup vs baseline: 2.6156x; 1.0128x over previous
//
#include <hip/hip_runtime.h>

// Modulated deformable conv2d, fp32.
// B=4, C=64, H=W=128, O=64, K=3x3, stride=1, pad=1, dil=1, og=1, groups=1.
//
// Round 4: kill register spills structurally. Rounds 2-3 died because
// addr[36]+wgt[36] per-thread arrays exceed what the allocator will keep in
// VGPRs. Reorder loops k-outer / c-inner: one tap's sampling state is only
// 4 offsets + 4 weights (8 regs), reused across all 64 channels by advancing
// the offsets by HW. Live state ~= acc[16] + 8 + temps ~= 45 VGPRs -> no
// spills at ANY allocation >= 48. Grid = 1024 pixel-groups x 4 o-chunks =
// 4096 waves = 4 waves/SIMD. Weights pre-transposed to [k][c][o] so each
// (k,c) row is one block-uniform s_load_dwordx16.

#define BB 4
#define CC 64
#define HH 128
#define WW 128
#define OO 64
#define KHW 3
#define KK 9
#define HW (HH * WW)
#define OPB 16  // output channels per block

__global__ void transpose_w_kernel(const float* __restrict__ w,
                                   float* __restrict__ wt) {
    int i = blockIdx.x * blockDim.x + threadIdx.x;
    if (i >= OO * CC * KK) return;
    // wt layout: [(k*64+c)*64 + o]
    int o  = i & (OO - 1);
    int kc = i >> 6;
    int c  = kc & (CC - 1);
    int k  = kc >> 6;
    wt[i] = w[(o * CC + c) * KK + k];
}

__global__ __launch_bounds__(64) void deform_conv_kernel(
    const float* __restrict__ x, const float* __restrict__ offset,
    const float* __restrict__ mask, const float* __restrict__ wt,
    const float* __restrict__ bias, float* __restrict__ out) {
    const int l        = threadIdx.x;           // lane = pixel within group
    const int ochunk   = blockIdx.x & 3;        // block-uniform o-chunk
    const int pixBlock = blockIdx.x >> 2;       // 1024 pixel groups
    const int b   = pixBlock >> 8;              // 256 groups per image
    const int rem = ((pixBlock & 255) << 6) + l;
    const int ho  = rem >> 7;
    const int wo  = rem & (WW - 1);

    const float* xb = x + b * (CC * HW);
    const int obase = ochunk * OPB;

    float acc[OPB];
#pragma unroll
    for (int oi = 0; oi < OPB; ++oi) acc[oi] = bias[obase + oi];

    for (int k = 0; k < KK; ++k) {
        // --- per-tap sampling state: 4 offsets + 4 folded weights ---
        float offy = offset[((b * (2 * KK) + 2 * k) * HW) + rem];
        float offx = offset[((b * (2 * KK) + 2 * k + 1) * HW) + rem];
        float m    = mask[((b * KK + k) * HW) + rem];
        float py = offy + (float)(k / KHW) + (float)(ho - 1);
        float px = offx + (float)(k % KHW) + (float)(wo - 1);
        float fy0 = floorf(py), fx0 = floorf(px);
        float ly = py - fy0, lx = px - fx0;
        int y0 = (int)fy0, x0 = (int)fx0;
        int y1 = y0 + 1, x1 = x0 + 1;
        bool vy0 = (y0 >= 0) && (y0 < HH);
        bool vy1 = (y1 >= 0) && (y1 < HH);
        bool vx0 = (x0 >= 0) && (x0 < WW);
        bool vx1 = (x1 >= 0) && (x1 < WW);
        int cy0 = min(max(y0, 0), HH - 1), cy1 = min(max(y1, 0), HH - 1);
        int cx0 = min(max(x0, 0), WW - 1), cx1 = min(max(x1, 0), WW - 1);
        int a0 = cy0 * WW + cx0;
        int a1 = cy0 * WW + cx1;
        int a2 = cy1 * WW + cx0;
        int a3 = cy1 * WW + cx1;
        float w0 = (vy0 && vx0) ? m * (1.0f - ly) * (1.0f - lx) : 0.0f;
        float w1 = (vy0 && vx1) ? m * (1.0f - ly) * lx : 0.0f;
        float w2 = (vy1 && vx0) ? m * ly * (1.0f - lx) : 0.0f;
        float w3 = (vy1 && vx1) ? m * ly * lx : 0.0f;

        const float* wk = wt + (k * CC) * OO + obase;  // block-uniform
#pragma unroll 4
        for (int c = 0; c < CC; ++c) {
            float val = w0 * xb[a0] + w1 * xb[a1] + w2 * xb[a2] + w3 * xb[a3];
            a0 += HW; a1 += HW; a2 += HW; a3 += HW;
            const float* wrow = wk + c * OO;  // one s_load_dwordx16
#pragma unroll
            for (int oi = 0; oi < OPB; ++oi) {
                acc[oi] = fmaf(val, wrow[oi], acc[oi]);
            }
        }
    }

    float* ob = out + (b * OO + obase) * HW + rem;
#pragma unroll
    for (int oi = 0; oi < OPB; ++oi) ob[oi * HW] = acc[oi];  // coalesced
}

extern "C" void kernel_launch(void* const* d_in, const int* in_sizes, int n_in,
                              void* d_out, int out_size, void* d_ws,
                              size_t ws_size, hipStream_t stream) {
    const float* x      = (const float*)d_in[0];
    const float* offset = (const float*)d_in[1];
    const float* mask   = (const float*)d_in[2];
    const float* weight = (const float*)d_in[3];
    const float* bias   = (const float*)d_in[4];
    float* out = (float*)d_out;
    float* wt  = (float*)d_ws;  // 64*576*4 = 147456 bytes

    int nw = OO * CC * KK;  // 36864
    transpose_w_kernel<<<(nw + 255) / 256, 256, 0, stream>>>(weight, wt);

    int nblocks = (BB * HW / 64) * (OO / OPB);  // 1024 * 4 = 4096
    deform_conv_kernel<<<nblocks, 64, 0, stream>>>(x, offset, mask, wt, bias,
                                                   out);
}

// Round 5
// 114.874 us; speedup vs baseline: 10.9828x; 4.1990x over previous
//
#include <hip/hip_runtime.h>

// Modulated deformable conv2d, fp32 in/out, bf16 MFMA core.
// B=4, C=64, H=W=128, O=64, K=3x3, stride=1, pad=1, dil=1, og=1, groups=1.
//
// Round 5: two structural fixes based on round-4 counters (FETCH 534 MB,
// VALUBusy 18% -> gather-locality-bound, never VALU-bound):
//  1. x -> NHWC bf16 in d_ws: one bilinear corner = 64 contiguous channels
//     (128 B, fully-used lines). Unique data 8 MB -> cache-resident.
//  2. GEMM on matrix cores: per block (64 pixels), per tap: 256 threads
//     sample 16 ch each into LDS V[64px][64c] (bf16, row pitch 72), then
//     each wave runs 2 Kchunks x 4 Ntiles mfma_f32_16x16x32_bf16.
// Fragment layouts (m89/m120-verified): A[m=lane&15][k=quad*8+j],
// B[k=quad*8+j][n=lane&15], D[row=quad*4+reg][col=lane&15].

#define BB 4
#define CC 64
#define HH 128
#define WW 128
#define OO 64
#define KHW 3
#define KK 9
#define HW (HH * WW)

typedef __bf16 bf16_t;
typedef bf16_t bf16x8 __attribute__((ext_vector_type(8)));
typedef float f32x4 __attribute__((ext_vector_type(4)));

// ---- x (NCHW fp32) -> xt (NHWC bf16), LDS-tiled transpose ----
__global__ __launch_bounds__(256) void nhwc_kernel(const float* __restrict__ x,
                                                   bf16_t* __restrict__ xt) {
    __shared__ float tile[64 * 65];
    const int t  = threadIdx.x;
    const int b  = blockIdx.x >> 8;
    const int p0 = (blockIdx.x & 255) << 6;
#pragma unroll
    for (int i = 0; i < 16; ++i) {
        int c = i * 4 + (t >> 6);
        int p = t & 63;
        tile[c * 65 + p] = x[(b * CC + c) * HW + p0 + p];  // coalesced read
    }
    __syncthreads();
#pragma unroll
    for (int i = 0; i < 16; ++i) {
        int p = i * 4 + (t >> 6);
        int c = t & 63;
        xt[(size_t)((b * HW) + p0 + p) * CC + c] = (bf16_t)tile[c * 65 + p];
    }
}

// ---- weight [O][C][3][3] fp32 -> B-fragment order bf16 ----
// wf element index: ((tap*2+q)*4+nt)*64*8 + lane*8 + j
//   holds W[o = nt*16 + (lane&15)][c = q*32 + (lane>>4)*8 + j][tap]
__global__ void wfrag_kernel(const float* __restrict__ w,
                             bf16_t* __restrict__ wf) {
    int i = blockIdx.x * blockDim.x + threadIdx.x;
    if (i >= OO * CC * KK) return;
    int j    = i & 7;
    int lane = (i >> 3) & 63;
    int nt   = (i >> 9) & 3;
    int q    = (i >> 11) & 1;
    int k    = i >> 12;
    int o = nt * 16 + (lane & 15);
    int c = q * 32 + ((lane >> 4) << 3) + j;
    wf[i] = (bf16_t)w[(o * CC + c) * KK + k];
}

__global__ __launch_bounds__(256) void deform_conv_mfma(
    const bf16_t* __restrict__ xt, const float* __restrict__ offset,
    const float* __restrict__ mask, const bf16x8* __restrict__ wf,
    const float* __restrict__ bias, float* __restrict__ out) {
    const int t       = threadIdx.x;
    const int b       = blockIdx.x >> 8;
    const int p0      = (blockIdx.x & 255) << 6;   // 64-pixel group
    const int p_local = t >> 2;                    // sampling: pixel
    const int c0      = (t & 3) << 4;              // sampling: 16-ch chunk
    const int rem     = p0 + p_local;
    const int ho      = rem >> 7;
    const int wo      = rem & (WW - 1);
    const int lane    = t & 63;
    const int wv      = t >> 6;
    const int m0      = wv << 4;                   // wave's 16-pixel strip
    const int col     = lane & 15;
    const int quad    = lane >> 4;

    __shared__ bf16_t V[2][64][72];                // double-buffered, padded

    const bf16_t* xb = xt + (size_t)b * HW * CC;

    f32x4 acc[4];
#pragma unroll
    for (int nt = 0; nt < 4; ++nt) acc[nt] = (f32x4){0.f, 0.f, 0.f, 0.f};

    for (int k = 0; k < KK; ++k) {
        // ---- sampling: this thread does 16 channels of one pixel ----
        float offy = offset[((b * (2 * KK) + 2 * k) * HW) + rem];
        float offx = offset[((b * (2 * KK) + 2 * k + 1) * HW) + rem];
        float mm   = mask[((b * KK + k) * HW) + rem];
        float py = offy + (float)(k / KHW) + (float)(ho - 1);
        float px = offx + (float)(k % KHW) + (float)(wo - 1);
        float fy0 = floorf(py), fx0 = floorf(px);
        float ly = py - fy0, lx = px - fx0;
        int y0 = (int)fy0, x0 = (int)fx0;
        int y1 = y0 + 1, x1 = x0 + 1;
        bool vy0 = (y0 >= 0) && (y0 < HH);
        bool vy1 = (y1 >= 0) && (y1 < HH);
        bool vx0 = (x0 >= 0) && (x0 < WW);
        bool vx1 = (x1 >= 0) && (x1 < WW);
        int cy0 = min(max(y0, 0), HH - 1), cy1 = min(max(y1, 0), HH - 1);
        int cx0 = min(max(x0, 0), WW - 1), cx1 = min(max(x1, 0), WW - 1);
        float w0 = (vy0 && vx0) ? mm * (1.0f - ly) * (1.0f - lx) : 0.0f;
        float w1 = (vy0 && vx1) ? mm * (1.0f - ly) * lx : 0.0f;
        float w2 = (vy1 && vx0) ? mm * ly * (1.0f - lx) : 0.0f;
        float w3 = (vy1 && vx1) ? mm * ly * lx : 0.0f;

        const bf16x8* A0 = (const bf16x8*)(xb + (cy0 * WW + cx0) * CC + c0);
        const bf16x8* A1 = (const bf16x8*)(xb + (cy0 * WW + cx1) * CC + c0);
        const bf16x8* A2 = (const bf16x8*)(xb + (cy1 * WW + cx0) * CC + c0);
        const bf16x8* A3 = (const bf16x8*)(xb + (cy1 * WW + cx1) * CC + c0);
        bf16x8 a0l = A0[0], a0h = A0[1];
        bf16x8 a1l = A1[0], a1h = A1[1];
        bf16x8 a2l = A2[0], a2h = A2[1];
        bf16x8 a3l = A3[0], a3h = A3[1];

        bf16x8 r0, r1;
#pragma unroll
        for (int i = 0; i < 8; ++i) {
            float v = w0 * (float)a0l[i] + w1 * (float)a1l[i] +
                      w2 * (float)a2l[i] + w3 * (float)a3l[i];
            r0[i] = (bf16_t)v;
        }
#pragma unroll
        for (int i = 0; i < 8; ++i) {
            float v = w0 * (float)a0h[i] + w1 * (float)a1h[i] +
                      w2 * (float)a2h[i] + w3 * (float)a3h[i];
            r1[i] = (bf16_t)v;
        }
        const int buf = k & 1;
        *(bf16x8*)(&V[buf][p_local][c0])     = r0;
        *(bf16x8*)(&V[buf][p_local][c0 + 8]) = r1;

        __syncthreads();  // tile k written; prior-tap reads were on other buf

        // ---- MFMA: this wave's 16 pixels x 64 outputs, K=64 (one tap) ----
#pragma unroll
        for (int q = 0; q < 2; ++q) {
            bf16x8 af = *(const bf16x8*)(&V[buf][m0 + col][q * 32 + quad * 8]);
#pragma unroll
            for (int nt = 0; nt < 4; ++nt) {
                bf16x8 bfg = wf[((k * 2 + q) * 4 + nt) * 64 + lane];
                acc[nt] = __builtin_amdgcn_mfma_f32_16x16x32_bf16(
                    af, bfg, acc[nt], 0, 0, 0);
            }
        }
    }

    // ---- epilogue: D[row=quad*4+reg][col] ; row -> pixel, col -> output ----
#pragma unroll
    for (int nt = 0; nt < 4; ++nt) {
        int o = nt * 16 + col;
        float bv = bias[o];
        f32x4 r = acc[nt];
        r.x += bv; r.y += bv; r.z += bv; r.w += bv;
        float* dst = out + (size_t)(b * OO + o) * HW + p0 + m0 + quad * 4;
        *(f32x4*)dst = r;  // 4 consecutive pixels, 16B aligned
    }
}

extern "C" void kernel_launch(void* const* d_in, const int* in_sizes, int n_in,
                              void* d_out, int out_size, void* d_ws,
                              size_t ws_size, hipStream_t stream) {
    const float* x      = (const float*)d_in[0];
    const float* offset = (const float*)d_in[1];
    const float* mask   = (const float*)d_in[2];
    const float* weight = (const float*)d_in[3];
    const float* bias   = (const float*)d_in[4];
    float* out = (float*)d_out;

    bf16_t* xt = (bf16_t*)d_ws;                       // 4*16384*64*2 = 8 MB
    bf16_t* wfr = (bf16_t*)((char*)d_ws + (size_t)BB * HW * CC * 2);  // 72 KB

    nhwc_kernel<<<BB * (HW / 64), 256, 0, stream>>>(x, xt);

    int nw = OO * CC * KK;  // 36864
    wfrag_kernel<<<(nw + 255) / 256, 256, 0, stream>>>(weight, wfr);

    deform_conv_mfma<<<BB * (HW / 64), 256, 0, stream>>>(
        xt, offset, mask, (const bf16x8*)wfr, bias, out);
}